// Round 1
// baseline (533.359 us; speedup 1.0000x reference)
//
#include <hip/hip_runtime.h>

// Problem constants (from reference)
#define TT 16384
#define NN 16
// Windowed-parallel scan parameters
#define W_WARM 512
#define CHUNK 64

#define RL(v, m) __int_as_float(__builtin_amdgcn_readlane(__float_as_int(v), (m)))

__device__ __forceinline__ float fsig(float x) {
    // sigmoid(x) = 1/(1+2^(-x*log2e))
    return __builtin_amdgcn_rcpf(1.0f + __builtin_amdgcn_exp2f(-1.4426950408889634f * x));
}
__device__ __forceinline__ float ftanh(float x) {
    // tanh(x) = 1 - 2/(1+2^(2x*log2e))
    return fmaf(-2.0f, __builtin_amdgcn_rcpf(1.0f + __builtin_amdgcn_exp2f(2.8853900817779268f * x)), 1.0f);
}

// ---------------------------------------------------------------------------
// Kernel 1: fixed matrices from a_list: fix = [Lsum, M0, M1, M2], Ml = Lhat_l @ Lsum
// ---------------------------------------------------------------------------
__global__ void k_fixed(const float* __restrict__ a, float* __restrict__ fix) {
    __shared__ float Lh[3][16][16];
    __shared__ float Ls[16][16];
    __shared__ float dsh[3][16];
    int tid = threadIdx.x;
    if (tid < 48) {
        int l = tid >> 4, j = tid & 15;
        float s = 0.f;
        for (int i = 0; i < 16; i++) s += a[l * 256 + i * 16 + j];
        dsh[l][j] = s;
    }
    __syncthreads();
    int i = tid >> 4, j = tid & 15;
    for (int l = 0; l < 3; l++) {
        float L = ((i == j) ? dsh[l][i] : 0.0f) - a[l * 256 + i * 16 + j];
        Lh[l][i][j] = L * rsqrtf(dsh[l][i]) * rsqrtf(dsh[l][j]);
    }
    __syncthreads();
    float ls = Lh[0][i][j] + Lh[1][i][j] + Lh[2][i][j];
    Ls[i][j] = ls;
    fix[i * 16 + j] = ls;
    __syncthreads();
    for (int l = 0; l < 3; l++) {
        float m = 0.f;
        for (int k = 0; k < 16; k++) m += Lh[l][i][k] * Ls[k][j];
        fix[(l + 1) * 256 + i * 16 + j] = m;
    }
}

// ---------------------------------------------------------------------------
// Kernel 2: per-t record precompute (parallel over t).
// PK layout (1088 f): [A 256][K1^T 256][K3^T 256][K5^T 256][u0 16][u2 16][u4 16][bh 16]
// compact  (320  f): [A 256][u0 16][u2 16][u4 16][bh 16]   (K read from gru_k in walker)
// ---------------------------------------------------------------------------
template <bool PK>
__global__ void k_prep(const float* __restrict__ inp, const float* __restrict__ wx_,
                       const float* __restrict__ bx_, const float* __restrict__ wh_,
                       const float* __restrict__ bh_, const float* __restrict__ gk,
                       const float* __restrict__ gb, float* __restrict__ ws) {
    __shared__ float sfix[1024];
    __shared__ float sxg[16][16];
    int tid = threadIdx.x;
    for (int idx = tid; idx < 1024; idx += 256) sfix[idx] = ws[idx];
    int tl = tid >> 4, n = tid & 15;
    int t = blockIdx.x * 16 + tl;
    __syncthreads();

    const int REC = PK ? 1088 : 320;
    const int UOF = PK ? 1024 : 256;
    float* rec = ws + 1024 + (size_t)t * REC;
    bool z0 = (t == 0);

    // A row n from wh coefficients
    const float* wh = wh_ + t * 13;
    float w0 = wh[0];
    float aI = wh[10], aL = wh[11] * w0;
    float wc = wh[12] * w0;
    float c0 = wc * w0, c1 = wc * wh[1], c2 = wc * wh[2];
    for (int m = 0; m < 16; m++) {
        float Av = aL * sfix[n * 16 + m] + c0 * sfix[256 + n * 16 + m] +
                   c1 * sfix[512 + n * 16 + m] + c2 * sfix[768 + n * 16 + m];
        if (m == n) Av += aI;
        rec[n * 16 + m] = z0 ? 0.f : Av;
    }

    // xg[n]
    float acc = bx_[t * 16 + n];
    for (int c = 0; c < 2; c++) {
        const float* wx = wx_ + t * 26 + c * 13;
        float yL = 0.f, y0 = 0.f, y1 = 0.f, y2 = 0.f;
        for (int m = 0; m < 16; m++) {
            float xm = inp[t * 32 + m * 2 + c];
            yL += sfix[n * 16 + m] * xm;
            y0 += sfix[256 + n * 16 + m] * xm;
            y1 += sfix[512 + n * 16 + m] * xm;
            y2 += sfix[768 + n * 16 + m] * xm;
        }
        float xn = inp[t * 32 + n * 2 + c];
        float b0 = wx[12] * wx[0];
        acc += wx[10] * xn + wx[11] * wx[0] * yL + b0 * (wx[0] * y0 + wx[1] * y1 + wx[2] * y2);
    }
    float xg = fmaxf(acc, 0.f);
    sxg[tl][n] = xg;
    __syncthreads();

    // u_q[n] = xg @ K_{2q} + B_{2q} + B_{2q+1}
    const float* Kb = gk + (size_t)t * 1536;
    const float* gbt = gb + (size_t)t * 96;
    for (int q = 0; q < 3; q++) {
        const float* K = Kb + (2 * q) * 256;
        float u = gbt[2 * q * 16 + n] + gbt[(2 * q + 1) * 16 + n];
        for (int m = 0; m < 16; m++) u += sxg[tl][m] * K[m * 16 + n];
        rec[UOF + q * 16 + n] = u;
    }
    rec[UOF + 48 + n] = z0 ? 0.f : bh_[t * 16 + n];

    if (PK) {
        // transposed K1,K3,K5 so walker lane n reads its column contiguously
        for (int jj = 0; jj < 3; jj++) {
            const float* K = Kb + (2 * jj + 1) * 256;
            float* dst = rec + 256 + jj * 256 + n * 16;
            for (int m = 0; m < 16; m++) dst[m] = K[m * 16 + n];
        }
    }
}

// ---------------------------------------------------------------------------
// Kernel 3: windowed sequential walker, 1 wave per block, CHUNK outputs/block
// ---------------------------------------------------------------------------
struct Regs {
    float WA[16];  // A row n
    float WB[16];  // K1^T col n (q even) / K3^T col n (q odd)
    float WC[16];  // K5^T col n
    float uRZ, u4, bh;
};

template <bool PK>
__device__ __forceinline__ void load_step(const float* __restrict__ recb,
                                          const float* __restrict__ gk, int t, int n, int q,
                                          Regs& R) {
    const float* rb = recb + (size_t)t * (PK ? 1088 : 320);
#pragma unroll
    for (int k = 0; k < 4; k++) ((float4*)R.WA)[k] = ((const float4*)(rb + n * 16))[k];
    if (PK) {
        const float* pb = rb + 256 + (q & 1) * 256 + n * 16;
        const float* pc = rb + 768 + n * 16;
#pragma unroll
        for (int k = 0; k < 4; k++) ((float4*)R.WB)[k] = ((const float4*)pb)[k];
#pragma unroll
        for (int k = 0; k < 4; k++) ((float4*)R.WC)[k] = ((const float4*)pc)[k];
        R.uRZ = rb[1024 + (q & 1) * 16 + n];
        R.u4 = rb[1056 + n];
        R.bh = rb[1072 + n];
    } else {
        const float* kb = gk + (size_t)t * 1536 + (1 + 2 * (q & 1)) * 256 + n;
        const float* kc = gk + (size_t)t * 1536 + 5 * 256 + n;
#pragma unroll
        for (int m = 0; m < 16; m++) {
            R.WB[m] = kb[m * 16];
            R.WC[m] = kc[m * 16];
        }
        R.uRZ = rb[256 + (q & 1) * 16 + n];
        R.u4 = rb[288 + n];
        R.bh = rb[304 + n];
    }
}

__device__ __forceinline__ void wstep(const Regs& R, float hs[16], int t, int t0, int lane, int n,
                                      float* __restrict__ out) {
    // hg = relu(A h + bh)
    float a0 = 0.f, a1 = 0.f, a2 = 0.f, a3 = 0.f;
#pragma unroll
    for (int m = 0; m < 16; m += 4) {
        a0 = fmaf(R.WA[m + 0], hs[m + 0], a0);
        a1 = fmaf(R.WA[m + 1], hs[m + 1], a1);
        a2 = fmaf(R.WA[m + 2], hs[m + 2], a2);
        a3 = fmaf(R.WA[m + 3], hs[m + 3], a3);
    }
    float hg = fmaxf((a0 + a1) + (a2 + a3) + R.bh, 0.f);
    float hgs[16];
#pragma unroll
    for (int m = 0; m < 16; m++) hgs[m] = RL(hg, m);
    // r (q even) | z (q odd)
    a0 = a1 = a2 = a3 = 0.f;
#pragma unroll
    for (int m = 0; m < 16; m += 4) {
        a0 = fmaf(R.WB[m + 0], hgs[m + 0], a0);
        a1 = fmaf(R.WB[m + 1], hgs[m + 1], a1);
        a2 = fmaf(R.WB[m + 2], hgs[m + 2], a2);
        a3 = fmaf(R.WB[m + 3], hgs[m + 3], a3);
    }
    float rz = fsig((a0 + a1) + (a2 + a3) + R.uRZ);
    float zsw = __shfl_xor(rz, 16);  // z into even quads
    float rhg = rz * hg;
    float rhgs[16];
#pragma unroll
    for (int m = 0; m < 16; m++) rhgs[m] = RL(rhg, m);
    // hc = tanh(u4 + K5^T (r.hg))
    a0 = a1 = a2 = a3 = 0.f;
#pragma unroll
    for (int m = 0; m < 16; m += 4) {
        a0 = fmaf(R.WC[m + 0], rhgs[m + 0], a0);
        a1 = fmaf(R.WC[m + 1], rhgs[m + 1], a1);
        a2 = fmaf(R.WC[m + 2], rhgs[m + 2], a2);
        a3 = fmaf(R.WC[m + 3], rhgs[m + 3], a3);
    }
    float hc = ftanh((a0 + a1) + (a2 + a3) + R.u4);
    float h = fmaf(zsw, hg - hc, hc);  // z*hg + (1-z)*hc
    if (t >= t0 && lane < 16) out[(size_t)t * 16 + n] = h;
#pragma unroll
    for (int m = 0; m < 16; m++) hs[m] = RL(h, m);
}

template <bool PK>
__global__ __launch_bounds__(64) void k_walk(const float* __restrict__ ws,
                                             const float* __restrict__ gk,
                                             float* __restrict__ out) {
    const float* recb = ws + 1024;
    int lane = threadIdx.x;
    int n = lane & 15;
    int q = lane >> 4;
    int t0 = blockIdx.x * CHUNK;
    int te = t0 + CHUNK;
    int ts = t0 - W_WARM;
    if (ts < 0) ts = 0;

    Regs Ra, Rb;
    load_step<PK>(recb, gk, ts, n, q, Ra);
    load_step<PK>(recb, gk, ts + 1, n, q, Rb);

    float hs[16];
#pragma unroll
    for (int m = 0; m < 16; m++) hs[m] = 0.f;

    for (int t = ts; t < te; t += 2) {  // (te - ts) always even
        wstep(Ra, hs, t, t0, lane, n, out);
        int tn = t + 2;
        load_step<PK>(recb, gk, tn < TT ? tn : TT - 1, n, q, Ra);
        wstep(Rb, hs, t + 1, t0, lane, n, out);
        int tm = t + 3;
        load_step<PK>(recb, gk, tm < TT ? tm : TT - 1, n, q, Rb);
    }
}

// ---------------------------------------------------------------------------
extern "C" void kernel_launch(void* const* d_in, const int* in_sizes, int n_in, void* d_out,
                              int out_size, void* d_ws, size_t ws_size, hipStream_t stream) {
    const float* inp = (const float*)d_in[0];
    const float* a = (const float*)d_in[1];
    const float* wx = (const float*)d_in[2];
    const float* bx = (const float*)d_in[3];
    const float* wh = (const float*)d_in[4];
    const float* bh = (const float*)d_in[5];
    const float* gk = (const float*)d_in[6];
    const float* gb = (const float*)d_in[7];
    float* out = (float*)d_out;
    float* ws = (float*)d_ws;

    size_t needPK = 4ull * (1024ull + (size_t)TT * 1088ull);  // ~71.3 MB
    bool pk = (ws_size >= needPK);

    k_fixed<<<dim3(1), dim3(256), 0, stream>>>(a, ws);
    if (pk) {
        k_prep<true><<<dim3(TT / 16), dim3(256), 0, stream>>>(inp, wx, bx, wh, bh, gk, gb, ws);
        k_walk<true><<<dim3(TT / CHUNK), dim3(64), 0, stream>>>(ws, gk, out);
    } else {
        k_prep<false><<<dim3(TT / 16), dim3(256), 0, stream>>>(inp, wx, bx, wh, bh, gk, gb, ws);
        k_walk<false><<<dim3(TT / CHUNK), dim3(64), 0, stream>>>(ws, gk, out);
    }
}

// Round 2
// 425.641 us; speedup vs baseline: 1.2531x; 1.2531x over previous
//
#include <hip/hip_runtime.h>

// Problem constants
#define TT 16384
#define W_WARM 512
#define CHUNK 64
#define RECF 1088               // floats per per-step record
#define RING_D 8                // LDS ring slots (prefetch distance 7)

#define RL(v, m) __int_as_float(__builtin_amdgcn_readlane(__float_as_int(v), (m)))

__device__ __forceinline__ float fsig(float x) {
    return __builtin_amdgcn_rcpf(1.0f + __builtin_amdgcn_exp2f(-1.4426950408889634f * x));
}
__device__ __forceinline__ float ftanh(float x) {
    return fmaf(-2.0f, __builtin_amdgcn_rcpf(1.0f + __builtin_amdgcn_exp2f(2.8853900817779268f * x)), 1.0f);
}

// ---------------------------------------------------------------------------
// Kernel 1: fixed matrices from a_list: fix = [Lsum, M0, M1, M2], Ml = Lhat_l @ Lsum
// ---------------------------------------------------------------------------
__global__ void k_fixed(const float* __restrict__ a, float* __restrict__ fix) {
    __shared__ float Lh[3][16][16];
    __shared__ float Ls[16][16];
    __shared__ float dsh[3][16];
    int tid = threadIdx.x;
    if (tid < 48) {
        int l = tid >> 4, j = tid & 15;
        float s = 0.f;
        for (int i = 0; i < 16; i++) s += a[l * 256 + i * 16 + j];
        dsh[l][j] = s;
    }
    __syncthreads();
    int i = tid >> 4, j = tid & 15;
    for (int l = 0; l < 3; l++) {
        float L = ((i == j) ? dsh[l][i] : 0.0f) - a[l * 256 + i * 16 + j];
        Lh[l][i][j] = L * rsqrtf(dsh[l][i]) * rsqrtf(dsh[l][j]);
    }
    __syncthreads();
    float ls = Lh[0][i][j] + Lh[1][i][j] + Lh[2][i][j];
    Ls[i][j] = ls;
    fix[i * 16 + j] = ls;
    __syncthreads();
    for (int l = 0; l < 3; l++) {
        float m = 0.f;
        for (int k = 0; k < 16; k++) m += Lh[l][i][k] * Ls[k][j];
        fix[(l + 1) * 256 + i * 16 + j] = m;
    }
}

// ---------------------------------------------------------------------------
// Kernel 2 (new): per-t record, LDS-staged, coalesced float4 output.
// Record (1088 f), XOR-swizzled 16B chunks within each 16x16 block:
//   [A 256][K1^T 256][K3^T 256][K5^T 256][ex 64: per-n {bh,uR,uZ,u4}]
// element (row n, m) of a block stored at n*16 + ((m>>2)^((n>>1)&3))*4 + (m&3)
// ---------------------------------------------------------------------------
__global__ __launch_bounds__(128) void k_prep2(const float* __restrict__ inp,
                                               const float* __restrict__ wx_,
                                               const float* __restrict__ bx_,
                                               const float* __restrict__ wh_,
                                               const float* __restrict__ bh_,
                                               const float* __restrict__ gk,
                                               const float* __restrict__ gb,
                                               float* __restrict__ ws) {
    __shared__ float sfix[1024];
    __shared__ float srec[8][RECF];
    __shared__ float sxg[8][16];
    int tid = threadIdx.x;
    for (int i = tid; i < 1024; i += 128) sfix[i] = ws[i];
    int tl = tid >> 4, n = tid & 15;
    int t = blockIdx.x * 8 + tl;
    __syncthreads();
    bool z0 = (t == 0);
    int sw = (n >> 1) & 3;

    // A row n
    const float* wh = wh_ + t * 13;
    float w0 = wh[0];
    float aI = wh[10], aL = wh[11] * w0;
    float wc = wh[12] * w0;
    float c0 = wc * w0, c1 = wc * wh[1], c2 = wc * wh[2];
    for (int m = 0; m < 16; m++) {
        float Av = aL * sfix[n * 16 + m] + c0 * sfix[256 + n * 16 + m] +
                   c1 * sfix[512 + n * 16 + m] + c2 * sfix[768 + n * 16 + m];
        if (m == n) Av += aI;
        srec[tl][n * 16 + ((((m >> 2) ^ sw) << 2) | (m & 3))] = z0 ? 0.f : Av;
    }

    // xg[n]
    float acc = bx_[t * 16 + n];
    for (int c = 0; c < 2; c++) {
        const float* wx = wx_ + t * 26 + c * 13;
        float yL = 0.f, y0 = 0.f, y1 = 0.f, y2 = 0.f;
        for (int m = 0; m < 16; m++) {
            float xm = inp[t * 32 + m * 2 + c];
            yL += sfix[n * 16 + m] * xm;
            y0 += sfix[256 + n * 16 + m] * xm;
            y1 += sfix[512 + n * 16 + m] * xm;
            y2 += sfix[768 + n * 16 + m] * xm;
        }
        float xn = inp[t * 32 + n * 2 + c];
        float b0 = wx[12] * wx[0];
        acc += wx[10] * xn + wx[11] * wx[0] * yL + b0 * (wx[0] * y0 + wx[1] * y1 + wx[2] * y2);
    }
    float xg = fmaxf(acc, 0.f);
    sxg[tl][n] = xg;
    __syncthreads();

    // u_q[n] = xg @ K_{2q} + B_{2q} + B_{2q+1}; extras packed per n
    const float* Kb = gk + (size_t)t * 1536;
    const float* gbt = gb + (size_t)t * 96;
    float u[3];
    for (int q = 0; q < 3; q++) {
        const float* K = Kb + 2 * q * 256;
        float s = gbt[2 * q * 16 + n] + gbt[(2 * q + 1) * 16 + n];
        for (int m = 0; m < 16; m++) s += sxg[tl][m] * K[m * 16 + n];
        u[q] = s;
    }
    srec[tl][1024 + n * 4 + 0] = z0 ? 0.f : bh_[t * 16 + n];
    srec[tl][1024 + n * 4 + 1] = u[0];
    srec[tl][1024 + n * 4 + 2] = u[1];
    srec[tl][1024 + n * 4 + 3] = u[2];

    // transposed K1,K3,K5 (col n -> contiguous, swizzled)
    for (int b = 0; b < 3; b++) {
        const float* K = Kb + (2 * b + 1) * 256;
        float* dst = &srec[tl][256 * (b + 1)];
        for (int m = 0; m < 16; m++)
            dst[n * 16 + ((((m >> 2) ^ sw) << 2) | (m & 3))] = K[m * 16 + n];
    }
    __syncthreads();

    // coalesced stream-out
    float4* gdst = (float4*)(ws + 1024 + (size_t)blockIdx.x * 8 * RECF);
    const float4* lsrc = (const float4*)&srec[0][0];
    for (int i = tid; i < 8 * RECF / 4; i += 128) gdst[i] = lsrc[i];
}

// ---------------------------------------------------------------------------
// Kernel 3 (new): walker with LDS ring + global_load_lds + explicit vmcnt
// ---------------------------------------------------------------------------
struct SReg {
    float WA[16], WB[16], WC[16], ex[4];  // ex = {bh, uR, uZ, u4}
};

__device__ __forceinline__ void fetch_rec(const float* __restrict__ g, float* l, int lane) {
    const float* gs = g + lane * 4;
#pragma unroll
    for (int i = 0; i < 4; i++)
        __builtin_amdgcn_global_load_lds(
            (const __attribute__((address_space(1))) unsigned int*)(gs + i * 256),
            (__attribute__((address_space(3))) unsigned int*)(l + i * 256), 16, 0, 0);
    if (lane < 16)
        __builtin_amdgcn_global_load_lds(
            (const __attribute__((address_space(1))) unsigned int*)(gs + 1024),
            (__attribute__((address_space(3))) unsigned int*)(l + 1024), 16, 0, 0);
}

__device__ __forceinline__ void lds_read(const float* s, int n, int q, int sw, SReg& R) {
#pragma unroll
    for (int k = 0; k < 4; k++)
        ((float4*)R.WA)[k] = *(const float4*)(s + n * 16 + ((k ^ sw) << 2));
    const float* b1 = s + 256 + ((q & 1) << 8);
#pragma unroll
    for (int k = 0; k < 4; k++)
        ((float4*)R.WB)[k] = *(const float4*)(b1 + n * 16 + ((k ^ sw) << 2));
    const float* b2 = s + 768;
#pragma unroll
    for (int k = 0; k < 4; k++)
        ((float4*)R.WC)[k] = *(const float4*)(b2 + n * 16 + ((k ^ sw) << 2));
    *(float4*)R.ex = *(const float4*)(s + 1024 + (n << 2));
}

__device__ __forceinline__ void wstep2(const SReg& R, float hs[16], int t, int t0, int lane,
                                       int n, int q, float* __restrict__ out) {
    float a0 = 0.f, a1 = 0.f, a2 = 0.f, a3 = 0.f;
#pragma unroll
    for (int m = 0; m < 16; m += 4) {
        a0 = fmaf(R.WA[m + 0], hs[m + 0], a0);
        a1 = fmaf(R.WA[m + 1], hs[m + 1], a1);
        a2 = fmaf(R.WA[m + 2], hs[m + 2], a2);
        a3 = fmaf(R.WA[m + 3], hs[m + 3], a3);
    }
    float hg = fmaxf((a0 + a1) + (a2 + a3) + R.ex[0], 0.f);
    float hgs[16];
#pragma unroll
    for (int m = 0; m < 16; m++) hgs[m] = RL(hg, m);
    a0 = a1 = a2 = a3 = 0.f;
#pragma unroll
    for (int m = 0; m < 16; m += 4) {
        a0 = fmaf(R.WB[m + 0], hgs[m + 0], a0);
        a1 = fmaf(R.WB[m + 1], hgs[m + 1], a1);
        a2 = fmaf(R.WB[m + 2], hgs[m + 2], a2);
        a3 = fmaf(R.WB[m + 3], hgs[m + 3], a3);
    }
    float uRZ = (q & 1) ? R.ex[2] : R.ex[1];
    float rz = fsig((a0 + a1) + (a2 + a3) + uRZ);
    float zsw = __shfl_xor(rz, 16);
    float rhg = rz * hg;
    float rhgs[16];
#pragma unroll
    for (int m = 0; m < 16; m++) rhgs[m] = RL(rhg, m);
    a0 = a1 = a2 = a3 = 0.f;
#pragma unroll
    for (int m = 0; m < 16; m += 4) {
        a0 = fmaf(R.WC[m + 0], rhgs[m + 0], a0);
        a1 = fmaf(R.WC[m + 1], rhgs[m + 1], a1);
        a2 = fmaf(R.WC[m + 2], rhgs[m + 2], a2);
        a3 = fmaf(R.WC[m + 3], rhgs[m + 3], a3);
    }
    float hc = ftanh((a0 + a1) + (a2 + a3) + R.ex[3]);
    float h = fmaf(zsw, hg - hc, hc);
    if (t >= t0 && lane < 16) out[(size_t)t * 16 + n] = h;
#pragma unroll
    for (int m = 0; m < 16; m++) hs[m] = RL(h, m);
}

__global__ __launch_bounds__(64) void k_walk2(const float* __restrict__ ws,
                                              float* __restrict__ out) {
    __shared__ float ring[RING_D * RECF];
    const float* recb = ws + 1024;
    int lane = threadIdx.x;
    int n = lane & 15, q = lane >> 4, sw = (n >> 1) & 3;
    int t0 = blockIdx.x * CHUNK, te = t0 + CHUNK;
    int ts = t0 - W_WARM;
    if (ts < 0) ts = 0;

    // prologue: fill 7 slots (5 loads each -> 35 outstanding)
#pragma unroll
    for (int i = 0; i < 7; i++)
        fetch_rec(recb + (size_t)(ts + i) * RECF, ring + ((ts + i) & 7) * RECF, lane);
    asm volatile("s_waitcnt vmcnt(30)" ::: "memory");  // slot ts landed
    SReg Ra, Rb;
    lds_read(ring + (ts & 7) * RECF, n, q, sw, Ra);

    float hs[16];
#pragma unroll
    for (int m = 0; m < 16; m++) hs[m] = 0.f;

    for (int t = ts; t < te; t += 2) {  // (te-ts) always even
        asm volatile("s_waitcnt vmcnt(25)" ::: "memory");  // slot t+1 landed
        lds_read(ring + ((t + 1) & 7) * RECF, n, q, sw, Rb);
        {
            int tf = t + 7;
            if (tf >= TT) tf = TT - 1;
            fetch_rec(recb + (size_t)tf * RECF, ring + ((t + 7) & 7) * RECF, lane);
        }
        wstep2(Ra, hs, t, t0, lane, n, q, out);
        asm volatile("s_waitcnt vmcnt(25)" ::: "memory");  // slot t+2 landed
        lds_read(ring + ((t + 2) & 7) * RECF, n, q, sw, Ra);
        {
            int tf = t + 8;
            if (tf >= TT) tf = TT - 1;
            fetch_rec(recb + (size_t)tf * RECF, ring + ((t + 8) & 7) * RECF, lane);
        }
        wstep2(Rb, hs, t + 1, t0, lane, n, q, out);
    }
}

// ---------------------------------------------------------------------------
// Fallback (compact records, round-1 structure) if ws is too small
// ---------------------------------------------------------------------------
__global__ void k_prep_c(const float* __restrict__ inp, const float* __restrict__ wx_,
                         const float* __restrict__ bx_, const float* __restrict__ wh_,
                         const float* __restrict__ bh_, const float* __restrict__ gk,
                         const float* __restrict__ gb, float* __restrict__ ws) {
    __shared__ float sfix[1024];
    __shared__ float sxg[16][16];
    int tid = threadIdx.x;
    for (int idx = tid; idx < 1024; idx += 256) sfix[idx] = ws[idx];
    int tl = tid >> 4, n = tid & 15;
    int t = blockIdx.x * 16 + tl;
    __syncthreads();

    float* rec = ws + 1024 + (size_t)t * 320;
    bool z0 = (t == 0);
    const float* wh = wh_ + t * 13;
    float w0 = wh[0];
    float aI = wh[10], aL = wh[11] * w0;
    float wc = wh[12] * w0;
    float c0 = wc * w0, c1 = wc * wh[1], c2 = wc * wh[2];
    for (int m = 0; m < 16; m++) {
        float Av = aL * sfix[n * 16 + m] + c0 * sfix[256 + n * 16 + m] +
                   c1 * sfix[512 + n * 16 + m] + c2 * sfix[768 + n * 16 + m];
        if (m == n) Av += aI;
        rec[n * 16 + m] = z0 ? 0.f : Av;
    }
    float acc = bx_[t * 16 + n];
    for (int c = 0; c < 2; c++) {
        const float* wx = wx_ + t * 26 + c * 13;
        float yL = 0.f, y0 = 0.f, y1 = 0.f, y2 = 0.f;
        for (int m = 0; m < 16; m++) {
            float xm = inp[t * 32 + m * 2 + c];
            yL += sfix[n * 16 + m] * xm;
            y0 += sfix[256 + n * 16 + m] * xm;
            y1 += sfix[512 + n * 16 + m] * xm;
            y2 += sfix[768 + n * 16 + m] * xm;
        }
        float xn = inp[t * 32 + n * 2 + c];
        float b0 = wx[12] * wx[0];
        acc += wx[10] * xn + wx[11] * wx[0] * yL + b0 * (wx[0] * y0 + wx[1] * y1 + wx[2] * y2);
    }
    float xg = fmaxf(acc, 0.f);
    sxg[tl][n] = xg;
    __syncthreads();
    const float* Kb = gk + (size_t)t * 1536;
    const float* gbt = gb + (size_t)t * 96;
    for (int qq = 0; qq < 3; qq++) {
        const float* K = Kb + (2 * qq) * 256;
        float u = gbt[2 * qq * 16 + n] + gbt[(2 * qq + 1) * 16 + n];
        for (int m = 0; m < 16; m++) u += sxg[tl][m] * K[m * 16 + n];
        rec[256 + qq * 16 + n] = u;
    }
    rec[304 + n] = z0 ? 0.f : bh_[t * 16 + n];
}

struct RegsC {
    float WA[16], WB[16], WC[16];
    float uRZ, u4, bh;
};

__device__ __forceinline__ void load_step_c(const float* __restrict__ recb,
                                            const float* __restrict__ gk, int t, int n, int q,
                                            RegsC& R) {
    const float* rb = recb + (size_t)t * 320;
#pragma unroll
    for (int k = 0; k < 4; k++) ((float4*)R.WA)[k] = ((const float4*)(rb + n * 16))[k];
    const float* kb = gk + (size_t)t * 1536 + (1 + 2 * (q & 1)) * 256 + n;
    const float* kc = gk + (size_t)t * 1536 + 5 * 256 + n;
#pragma unroll
    for (int m = 0; m < 16; m++) {
        R.WB[m] = kb[m * 16];
        R.WC[m] = kc[m * 16];
    }
    R.uRZ = rb[256 + (q & 1) * 16 + n];
    R.u4 = rb[288 + n];
    R.bh = rb[304 + n];
}

__device__ __forceinline__ void wstep_c(const RegsC& R, float hs[16], int t, int t0, int lane,
                                        int n, float* __restrict__ out) {
    float a0 = 0.f, a1 = 0.f, a2 = 0.f, a3 = 0.f;
#pragma unroll
    for (int m = 0; m < 16; m += 4) {
        a0 = fmaf(R.WA[m + 0], hs[m + 0], a0);
        a1 = fmaf(R.WA[m + 1], hs[m + 1], a1);
        a2 = fmaf(R.WA[m + 2], hs[m + 2], a2);
        a3 = fmaf(R.WA[m + 3], hs[m + 3], a3);
    }
    float hg = fmaxf((a0 + a1) + (a2 + a3) + R.bh, 0.f);
    float hgs[16];
#pragma unroll
    for (int m = 0; m < 16; m++) hgs[m] = RL(hg, m);
    a0 = a1 = a2 = a3 = 0.f;
#pragma unroll
    for (int m = 0; m < 16; m += 4) {
        a0 = fmaf(R.WB[m + 0], hgs[m + 0], a0);
        a1 = fmaf(R.WB[m + 1], hgs[m + 1], a1);
        a2 = fmaf(R.WB[m + 2], hgs[m + 2], a2);
        a3 = fmaf(R.WB[m + 3], hgs[m + 3], a3);
    }
    float rz = fsig((a0 + a1) + (a2 + a3) + R.uRZ);
    float zsw = __shfl_xor(rz, 16);
    float rhg = rz * hg;
    float rhgs[16];
#pragma unroll
    for (int m = 0; m < 16; m++) rhgs[m] = RL(rhg, m);
    a0 = a1 = a2 = a3 = 0.f;
#pragma unroll
    for (int m = 0; m < 16; m += 4) {
        a0 = fmaf(R.WC[m + 0], rhgs[m + 0], a0);
        a1 = fmaf(R.WC[m + 1], rhgs[m + 1], a1);
        a2 = fmaf(R.WC[m + 2], rhgs[m + 2], a2);
        a3 = fmaf(R.WC[m + 3], rhgs[m + 3], a3);
    }
    float hc = ftanh((a0 + a1) + (a2 + a3) + R.u4);
    float h = fmaf(zsw, hg - hc, hc);
    if (t >= t0 && lane < 16) out[(size_t)t * 16 + n] = h;
#pragma unroll
    for (int m = 0; m < 16; m++) hs[m] = RL(h, m);
}

__global__ __launch_bounds__(64) void k_walk_c(const float* __restrict__ ws,
                                               const float* __restrict__ gk,
                                               float* __restrict__ out) {
    const float* recb = ws + 1024;
    int lane = threadIdx.x;
    int n = lane & 15;
    int q = lane >> 4;
    int t0 = blockIdx.x * CHUNK;
    int te = t0 + CHUNK;
    int ts = t0 - W_WARM;
    if (ts < 0) ts = 0;
    RegsC Ra, Rb;
    load_step_c(recb, gk, ts, n, q, Ra);
    load_step_c(recb, gk, ts + 1, n, q, Rb);
    float hs[16];
#pragma unroll
    for (int m = 0; m < 16; m++) hs[m] = 0.f;
    for (int t = ts; t < te; t += 2) {
        wstep_c(Ra, hs, t, t0, lane, n, out);
        int tn = t + 2;
        load_step_c(recb, gk, tn < TT ? tn : TT - 1, n, q, Ra);
        wstep_c(Rb, hs, t + 1, t0, lane, n, out);
        int tm = t + 3;
        load_step_c(recb, gk, tm < TT ? tm : TT - 1, n, q, Rb);
    }
}

// ---------------------------------------------------------------------------
extern "C" void kernel_launch(void* const* d_in, const int* in_sizes, int n_in, void* d_out,
                              int out_size, void* d_ws, size_t ws_size, hipStream_t stream) {
    const float* inp = (const float*)d_in[0];
    const float* a = (const float*)d_in[1];
    const float* wx = (const float*)d_in[2];
    const float* bx = (const float*)d_in[3];
    const float* wh = (const float*)d_in[4];
    const float* bh = (const float*)d_in[5];
    const float* gk = (const float*)d_in[6];
    const float* gb = (const float*)d_in[7];
    float* out = (float*)d_out;
    float* ws = (float*)d_ws;

    size_t need = 4ull * (1024ull + (size_t)TT * RECF);  // ~71.3 MB
    k_fixed<<<dim3(1), dim3(256), 0, stream>>>(a, ws);
    if (ws_size >= need) {
        k_prep2<<<dim3(TT / 8), dim3(128), 0, stream>>>(inp, wx, bx, wh, bh, gk, gb, ws);
        k_walk2<<<dim3(TT / CHUNK), dim3(64), 0, stream>>>(ws, out);
    } else {
        k_prep_c<<<dim3(TT / 16), dim3(256), 0, stream>>>(inp, wx, bx, wh, bh, gk, gb, ws);
        k_walk_c<<<dim3(TT / CHUNK), dim3(64), 0, stream>>>(ws, gk, out);
    }
}

// Round 5
// 416.059 us; speedup vs baseline: 1.2819x; 1.0230x over previous
//
#include <hip/hip_runtime.h>

// Problem constants
#define TT 16384
#define W_WARM 384
#define CHUNK 64
#define RECF 1088               // floats per per-step record
#define RECB 4352               // bytes per record

#define RL(v, m) __int_as_float(__builtin_amdgcn_readlane(__float_as_int(v), (m)))
// vmcnt accounting (loads newer than the slot we need): 5 slots x 5 loads = 25.
// Correct whether or not interleaved stores retire in order.
#define VMWAIT25() asm volatile("s_waitcnt vmcnt(25)")
#define VMWAIT30() asm volatile("s_waitcnt vmcnt(30)")
// DS ops retire in-order; after issuing 13 reads for the next slot, waiting to
// <=13 outstanding guarantees the previous slot's 13 reads have completed.
#define LGKMWAIT13() asm volatile("s_waitcnt lgkmcnt(13)")
// Tie each component so consumers cannot be scheduled above the preceding wait.
#define LAUNDER(v) asm volatile("" : "+v"((v).x), "+v"((v).y), "+v"((v).z), "+v"((v).w))

__device__ __forceinline__ float fsig(float x) {
    return __builtin_amdgcn_rcpf(1.0f + __builtin_amdgcn_exp2f(-1.4426950408889634f * x));
}
__device__ __forceinline__ float ftanh(float x) {
    return fmaf(-2.0f, __builtin_amdgcn_rcpf(1.0f + __builtin_amdgcn_exp2f(2.8853900817779268f * x)), 1.0f);
}

// ---------------------------------------------------------------------------
// Kernel 1: fixed matrices from a_list: fix = [Lsum, M0, M1, M2]
// ---------------------------------------------------------------------------
__global__ void k_fixed(const float* __restrict__ a, float* __restrict__ fix) {
    __shared__ float Lh[3][16][16];
    __shared__ float Ls[16][16];
    __shared__ float dsh[3][16];
    int tid = threadIdx.x;
    if (tid < 48) {
        int l = tid >> 4, j = tid & 15;
        float s = 0.f;
        for (int i = 0; i < 16; i++) s += a[l * 256 + i * 16 + j];
        dsh[l][j] = s;
    }
    __syncthreads();
    int i = tid >> 4, j = tid & 15;
    for (int l = 0; l < 3; l++) {
        float L = ((i == j) ? dsh[l][i] : 0.0f) - a[l * 256 + i * 16 + j];
        Lh[l][i][j] = L * rsqrtf(dsh[l][i]) * rsqrtf(dsh[l][j]);
    }
    __syncthreads();
    float ls = Lh[0][i][j] + Lh[1][i][j] + Lh[2][i][j];
    Ls[i][j] = ls;
    fix[i * 16 + j] = ls;
    __syncthreads();
    for (int l = 0; l < 3; l++) {
        float m = 0.f;
        for (int k = 0; k < 16; k++) m += Lh[l][i][k] * Ls[k][j];
        fix[(l + 1) * 256 + i * 16 + j] = m;
    }
}

// ---------------------------------------------------------------------------
// Kernel 2: per-t record precompute; gru_k staged through LDS (coalesced).
// Record (1088 f), 16B-chunk XOR swizzle within each 16x16 block:
//   [A 256][K1^T 256][K3^T 256][K5^T 256][ex 64: per-n {bh,uR,uZ,u4}]
// ---------------------------------------------------------------------------
__global__ __launch_bounds__(128) void k_prep3(const float* __restrict__ inp,
                                               const float* __restrict__ wx_,
                                               const float* __restrict__ bx_,
                                               const float* __restrict__ wh_,
                                               const float* __restrict__ bh_,
                                               const float* __restrict__ gk,
                                               const float* __restrict__ gb,
                                               float* __restrict__ ws) {
    __shared__ float sfix[1024];
    __shared__ float srec[8][RECF];
    __shared__ float sgk[8][768];
    __shared__ float sxg[8][16];
    int tid = threadIdx.x;
    int t_base = blockIdx.x * 8;
    for (int i = tid; i < 1024; i += 128) sfix[i] = ws[i];
    // phase 1: even K matrices (K0,K2,K4) coalesced into LDS
    {
        float4* dst = (float4*)&sgk[0][0];
        const float4* src = (const float4*)gk;
        for (int i = tid; i < 1536; i += 128) {
            int tl2 = i / 192, r = i - tl2 * 192;
            int mtx = r >> 6, w = r & 63;
            dst[i] = src[(size_t)(t_base + tl2) * 384 + mtx * 128 + w];
        }
    }
    __syncthreads();
    int tl = tid >> 4, n = tid & 15;
    int t = t_base + tl;
    bool z0 = (t == 0);
    int sw = (n >> 1) & 3;

    // A row n
    const float* wh = wh_ + t * 13;
    float w0 = wh[0];
    float aI = wh[10], aL = wh[11] * w0;
    float wc = wh[12] * w0;
    float c0 = wc * w0, c1 = wc * wh[1], c2 = wc * wh[2];
    for (int m = 0; m < 16; m++) {
        float Av = aL * sfix[n * 16 + m] + c0 * sfix[256 + n * 16 + m] +
                   c1 * sfix[512 + n * 16 + m] + c2 * sfix[768 + n * 16 + m];
        if (m == n) Av += aI;
        srec[tl][n * 16 + ((((m >> 2) ^ sw) << 2) | (m & 3))] = z0 ? 0.f : Av;
    }

    // xg[n]
    float acc = bx_[t * 16 + n];
    for (int c = 0; c < 2; c++) {
        const float* wx = wx_ + t * 26 + c * 13;
        float yL = 0.f, y0 = 0.f, y1 = 0.f, y2 = 0.f;
        for (int m = 0; m < 16; m++) {
            float xm = inp[t * 32 + m * 2 + c];
            yL += sfix[n * 16 + m] * xm;
            y0 += sfix[256 + n * 16 + m] * xm;
            y1 += sfix[512 + n * 16 + m] * xm;
            y2 += sfix[768 + n * 16 + m] * xm;
        }
        float xn = inp[t * 32 + n * 2 + c];
        float b0 = wx[12] * wx[0];
        acc += wx[10] * xn + wx[11] * wx[0] * yL + b0 * (wx[0] * y0 + wx[1] * y1 + wx[2] * y2);
    }
    float xg = fmaxf(acc, 0.f);
    sxg[tl][n] = xg;
    __syncthreads();

    // u_q[n] = xg @ K_{2q} + B_{2q} + B_{2q+1}  (K from LDS)
    const float* gbt = gb + (size_t)t * 96;
    float u[3];
    for (int qq = 0; qq < 3; qq++) {
        const float* K = &sgk[tl][qq * 256];
        float s = gbt[2 * qq * 16 + n] + gbt[(2 * qq + 1) * 16 + n];
        for (int m = 0; m < 16; m++) s += sxg[tl][m] * K[m * 16 + n];
        u[qq] = s;
    }
    srec[tl][1024 + n * 4 + 0] = z0 ? 0.f : bh_[t * 16 + n];
    srec[tl][1024 + n * 4 + 1] = u[0];
    srec[tl][1024 + n * 4 + 2] = u[1];
    srec[tl][1024 + n * 4 + 3] = u[2];
    __syncthreads();
    // phase 2: odd K matrices (K1,K3,K5) coalesced into LDS (overwrite)
    {
        float4* dst = (float4*)&sgk[0][0];
        const float4* src = (const float4*)gk;
        for (int i = tid; i < 1536; i += 128) {
            int tl2 = i / 192, r = i - tl2 * 192;
            int mtx = r >> 6, w = r & 63;
            dst[i] = src[(size_t)(t_base + tl2) * 384 + mtx * 128 + 64 + w];
        }
    }
    __syncthreads();
    // transpose odd Ks (col n -> contiguous, swizzled)
    for (int b = 0; b < 3; b++) {
        const float* K = &sgk[tl][b * 256];
        float* d = &srec[tl][256 * (b + 1)];
        for (int m = 0; m < 16; m++)
            d[n * 16 + ((((m >> 2) ^ sw) << 2) | (m & 3))] = K[m * 16 + n];
    }
    __syncthreads();
    // coalesced stream-out
    float4* gdst = (float4*)(ws + 1024 + (size_t)t_base * RECF);
    const float4* lsrc = (const float4*)&srec[0][0];
    for (int i = tid; i < 8 * RECF / 4; i += 128) gdst[i] = lsrc[i];
}

// ---------------------------------------------------------------------------
// Kernel 3: walker. All LDS reads are opaque inline asm; manual vmcnt/lgkmcnt.
// ---------------------------------------------------------------------------
struct SReg {
    float4 A0, A1, A2, A3, B0, B1, B2, B3, C0, C1, C2, C3, ex;  // ex={bh,uR,uZ,u4}
};

template <int OFF>
__device__ __forceinline__ float4 dsr(unsigned a) {
    float4 d;
    asm volatile("ds_read_b128 %0, %1 offset:%2" : "=v"(d) : "v"(a), "i"(OFF));
    return d;
}

template <int SLOT>
__device__ __forceinline__ void read_slot(const unsigned aA[4], const unsigned aB[4],
                                          unsigned aex, SReg& R) {
    constexpr int B = SLOT * RECB;
    R.A0 = dsr<B>(aA[0]);
    R.A1 = dsr<B>(aA[1]);
    R.A2 = dsr<B>(aA[2]);
    R.A3 = dsr<B>(aA[3]);
    R.B0 = dsr<B>(aB[0]);
    R.B1 = dsr<B>(aB[1]);
    R.B2 = dsr<B>(aB[2]);
    R.B3 = dsr<B>(aB[3]);
    R.C0 = dsr<B + 3072>(aA[0]);
    R.C1 = dsr<B + 3072>(aA[1]);
    R.C2 = dsr<B + 3072>(aA[2]);
    R.C3 = dsr<B + 3072>(aA[3]);
    R.ex = dsr<B>(aex);
}

__device__ __forceinline__ void gate(SReg& R) {
    LAUNDER(R.A0);
    LAUNDER(R.A1);
    LAUNDER(R.A2);
    LAUNDER(R.A3);
    LAUNDER(R.B0);
    LAUNDER(R.B1);
    LAUNDER(R.B2);
    LAUNDER(R.B3);
    LAUNDER(R.C0);
    LAUNDER(R.C1);
    LAUNDER(R.C2);
    LAUNDER(R.C3);
    LAUNDER(R.ex);
}

// loff = byte offset of the destination slot within LDS (ring base is offset 0
// via ptrtoint truncation; AS(3) pointers built from integers -> no addrspacecast)
__device__ __forceinline__ void fetch_rec(const float* __restrict__ g, unsigned loff, int lane) {
    const float* gs = g + lane * 4;
#pragma unroll
    for (int i = 0; i < 4; i++)
        __builtin_amdgcn_global_load_lds(
            (const __attribute__((address_space(1))) unsigned int*)(gs + i * 256),
            (__attribute__((address_space(3))) unsigned int*)(unsigned)(loff + i * 1024u), 16, 0,
            0);
    if (lane < 16)
        __builtin_amdgcn_global_load_lds(
            (const __attribute__((address_space(1))) unsigned int*)(gs + 1024),
            (__attribute__((address_space(3))) unsigned int*)(unsigned)(loff + 4096u), 16, 0, 0);
}

__device__ __forceinline__ float dot16(const float4& x0, const float4& x1, const float4& x2,
                                       const float4& x3, const float h[16]) {
    float a0 = x0.x * h[0];
    float a1 = x0.y * h[1];
    float a2 = x0.z * h[2];
    float a3 = x0.w * h[3];
    a0 = fmaf(x1.x, h[4], a0);
    a1 = fmaf(x1.y, h[5], a1);
    a2 = fmaf(x1.z, h[6], a2);
    a3 = fmaf(x1.w, h[7], a3);
    a0 = fmaf(x2.x, h[8], a0);
    a1 = fmaf(x2.y, h[9], a1);
    a2 = fmaf(x2.z, h[10], a2);
    a3 = fmaf(x2.w, h[11], a3);
    a0 = fmaf(x3.x, h[12], a0);
    a1 = fmaf(x3.y, h[13], a1);
    a2 = fmaf(x3.z, h[14], a2);
    a3 = fmaf(x3.w, h[15], a3);
    return (a0 + a1) + (a2 + a3);
}

__device__ __forceinline__ void wstep(const SReg& R, float hs[16], int t, int t0, int q, int n,
                                      float* __restrict__ out) {
    // hg = relu(A h + bh)
    float hg = fmaxf(dot16(R.A0, R.A1, R.A2, R.A3, hs) + R.ex.x, 0.f);
    float hgs[16];
#pragma unroll
    for (int m = 0; m < 16; m++) hgs[m] = RL(hg, m);
    // q even: r | q odd: z
    float uRZ = (q & 1) ? R.ex.z : R.ex.y;
    float rz = fsig(dot16(R.B0, R.B1, R.B2, R.B3, hgs) + uRZ);
    float rhg = rz * hg;  // valid on even-q lanes (r*hg)
    float rhgs[16];
#pragma unroll
    for (int m = 0; m < 16; m++) rhgs[m] = RL(rhg, m);  // lanes 0..15 (q=0)
    float hc = ftanh(dot16(R.C0, R.C1, R.C2, R.C3, rhgs) + R.ex.w);
    float h = fmaf(rz, hg - hc, hc);  // valid on odd-q lanes (rz=z)
    if (q == 1 && t >= t0) out[(size_t)t * 16 + n] = h;
#pragma unroll
    for (int m = 0; m < 16; m++) hs[m] = RL(h, 16 + m);  // broadcast from q=1 lanes
}

template <int U>
__device__ __forceinline__ void half_step(SReg& cur, SReg& nxt, int t, int t0,
                                          const unsigned aA[4], const unsigned aB[4],
                                          unsigned aex, const float* __restrict__ recb,
                                          int lane, int n, int q, float hs[16],
                                          float* __restrict__ out) {
    VMWAIT25();                              // slot t+1 landed in LDS
    read_slot<(U + 1) & 7>(aA, aB, aex, nxt);
    LGKMWAIT13();                            // cur's 13 reads (issued last half) done
    gate(cur);                               // pin uses after the wait
    int tf = t + 7;
    if (tf > TT - 1) tf = TT - 1;
    fetch_rec(recb + (size_t)tf * RECF, ((U + 7) & 7) * RECB, lane);
    wstep(cur, hs, t, t0, q, n, out);
}

__global__ __launch_bounds__(64) void k_walk3(const float* __restrict__ ws,
                                              float* __restrict__ out) {
    __shared__ float ring[8 * RECF];
    const float* recb = ws + 1024;
    int lane = threadIdx.x;
    int n = lane & 15, q = lane >> 4, sw = (n >> 1) & 3;
    int t0 = blockIdx.x * CHUNK, te = t0 + CHUNK;
    int ts = t0 - W_WARM;
    if (ts < 0) ts = 0;  // ts is always a multiple of 8

    // Flat LDS addresses have the DS offset in the low 32 bits on gfx9 — plain
    // ptrtoint truncation, NO addrspacecast (which emits an unfoldable null-check).
    unsigned ring0 = (unsigned)(unsigned long long)(void*)ring;
    unsigned aA[4], aB[4];
#pragma unroll
    for (int k = 0; k < 4; k++) {
        aA[k] = ring0 + n * 64 + 16 * (k ^ sw);
        aB[k] = aA[k] + 1024 + (q & 1) * 1024;
    }
    unsigned aex = ring0 + 4096 + 16 * n;

    // prologue: fill 7 slots (35 loads in flight). ring base LDS offset == ring0.
#pragma unroll
    for (int i = 0; i < 7; i++)
        fetch_rec(recb + (size_t)(ts + i) * RECF, ring0 + i * RECB, lane);
    VMWAIT30();  // slot 0 landed (30 newer loads may remain)
    SReg Ra, Rb;
    read_slot<0>(aA, aB, aex, Ra);
    LGKMWAIT13();  // (13 outstanding == slot 0's own reads... drain below)
    asm volatile("s_waitcnt lgkmcnt(0)");
    gate(Ra);

    float hs[16];
#pragma unroll
    for (int m = 0; m < 16; m++) hs[m] = 0.f;

    for (int t = ts; t < te; t += 8) {
        half_step<0>(Ra, Rb, t + 0, t0, aA, aB, aex, recb, lane, n, q, hs, out);
        half_step<1>(Rb, Ra, t + 1, t0, aA, aB, aex, recb, lane, n, q, hs, out);
        half_step<2>(Ra, Rb, t + 2, t0, aA, aB, aex, recb, lane, n, q, hs, out);
        half_step<3>(Rb, Ra, t + 3, t0, aA, aB, aex, recb, lane, n, q, hs, out);
        half_step<4>(Ra, Rb, t + 4, t0, aA, aB, aex, recb, lane, n, q, hs, out);
        half_step<5>(Rb, Ra, t + 5, t0, aA, aB, aex, recb, lane, n, q, hs, out);
        half_step<6>(Ra, Rb, t + 6, t0, aA, aB, aex, recb, lane, n, q, hs, out);
        half_step<7>(Rb, Ra, t + 7, t0, aA, aB, aex, recb, lane, n, q, hs, out);
    }
}

// ---------------------------------------------------------------------------
// Fallback (compact records) if ws is too small
// ---------------------------------------------------------------------------
__global__ void k_prep_c(const float* __restrict__ inp, const float* __restrict__ wx_,
                         const float* __restrict__ bx_, const float* __restrict__ wh_,
                         const float* __restrict__ bh_, const float* __restrict__ gk,
                         const float* __restrict__ gb, float* __restrict__ ws) {
    __shared__ float sfix[1024];
    __shared__ float sxg[16][16];
    int tid = threadIdx.x;
    for (int idx = tid; idx < 1024; idx += 256) sfix[idx] = ws[idx];
    int tl = tid >> 4, n = tid & 15;
    int t = blockIdx.x * 16 + tl;
    __syncthreads();
    float* rec = ws + 1024 + (size_t)t * 320;
    bool z0 = (t == 0);
    const float* wh = wh_ + t * 13;
    float w0 = wh[0];
    float aI = wh[10], aL = wh[11] * w0;
    float wc = wh[12] * w0;
    float c0 = wc * w0, c1 = wc * wh[1], c2 = wc * wh[2];
    for (int m = 0; m < 16; m++) {
        float Av = aL * sfix[n * 16 + m] + c0 * sfix[256 + n * 16 + m] +
                   c1 * sfix[512 + n * 16 + m] + c2 * sfix[768 + n * 16 + m];
        if (m == n) Av += aI;
        rec[n * 16 + m] = z0 ? 0.f : Av;
    }
    float acc = bx_[t * 16 + n];
    for (int c = 0; c < 2; c++) {
        const float* wx = wx_ + t * 26 + c * 13;
        float yL = 0.f, y0 = 0.f, y1 = 0.f, y2 = 0.f;
        for (int m = 0; m < 16; m++) {
            float xm = inp[t * 32 + m * 2 + c];
            yL += sfix[n * 16 + m] * xm;
            y0 += sfix[256 + n * 16 + m] * xm;
            y1 += sfix[512 + n * 16 + m] * xm;
            y2 += sfix[768 + n * 16 + m] * xm;
        }
        float xn = inp[t * 32 + n * 2 + c];
        float b0 = wx[12] * wx[0];
        acc += wx[10] * xn + wx[11] * wx[0] * yL + b0 * (wx[0] * y0 + wx[1] * y1 + wx[2] * y2);
    }
    float xg = fmaxf(acc, 0.f);
    sxg[tl][n] = xg;
    __syncthreads();
    const float* Kb = gk + (size_t)t * 1536;
    const float* gbt = gb + (size_t)t * 96;
    for (int qq = 0; qq < 3; qq++) {
        const float* K = Kb + (2 * qq) * 256;
        float u = gbt[2 * qq * 16 + n] + gbt[(2 * qq + 1) * 16 + n];
        for (int m = 0; m < 16; m++) u += sxg[tl][m] * K[m * 16 + n];
        rec[256 + qq * 16 + n] = u;
    }
    rec[304 + n] = z0 ? 0.f : bh_[t * 16 + n];
}

struct RegsC {
    float WA[16], WB[16], WC[16];
    float uRZ, u4, bh;
};

__device__ __forceinline__ void load_step_c(const float* __restrict__ recb,
                                            const float* __restrict__ gk, int t, int n, int q,
                                            RegsC& R) {
    const float* rb = recb + (size_t)t * 320;
#pragma unroll
    for (int k = 0; k < 4; k++) ((float4*)R.WA)[k] = ((const float4*)(rb + n * 16))[k];
    const float* kb = gk + (size_t)t * 1536 + (1 + 2 * (q & 1)) * 256 + n;
    const float* kc = gk + (size_t)t * 1536 + 5 * 256 + n;
#pragma unroll
    for (int m = 0; m < 16; m++) {
        R.WB[m] = kb[m * 16];
        R.WC[m] = kc[m * 16];
    }
    R.uRZ = rb[256 + (q & 1) * 16 + n];
    R.u4 = rb[288 + n];
    R.bh = rb[304 + n];
}

__device__ __forceinline__ void wstep_c(const RegsC& R, float hs[16], int t, int t0, int lane,
                                        int n, float* __restrict__ out) {
    float a0 = 0.f, a1 = 0.f, a2 = 0.f, a3 = 0.f;
#pragma unroll
    for (int m = 0; m < 16; m += 4) {
        a0 = fmaf(R.WA[m + 0], hs[m + 0], a0);
        a1 = fmaf(R.WA[m + 1], hs[m + 1], a1);
        a2 = fmaf(R.WA[m + 2], hs[m + 2], a2);
        a3 = fmaf(R.WA[m + 3], hs[m + 3], a3);
    }
    float hg = fmaxf((a0 + a1) + (a2 + a3) + R.bh, 0.f);
    float hgs[16];
#pragma unroll
    for (int m = 0; m < 16; m++) hgs[m] = RL(hg, m);
    a0 = a1 = a2 = a3 = 0.f;
#pragma unroll
    for (int m = 0; m < 16; m += 4) {
        a0 = fmaf(R.WB[m + 0], hgs[m + 0], a0);
        a1 = fmaf(R.WB[m + 1], hgs[m + 1], a1);
        a2 = fmaf(R.WB[m + 2], hgs[m + 2], a2);
        a3 = fmaf(R.WB[m + 3], hgs[m + 3], a3);
    }
    float rz = fsig((a0 + a1) + (a2 + a3) + R.uRZ);
    float zsw = __shfl_xor(rz, 16);
    float rhg = rz * hg;
    float rhgs[16];
#pragma unroll
    for (int m = 0; m < 16; m++) rhgs[m] = RL(rhg, m);
    a0 = a1 = a2 = a3 = 0.f;
#pragma unroll
    for (int m = 0; m < 16; m += 4) {
        a0 = fmaf(R.WC[m + 0], rhgs[m + 0], a0);
        a1 = fmaf(R.WC[m + 1], rhgs[m + 1], a1);
        a2 = fmaf(R.WC[m + 2], rhgs[m + 2], a2);
        a3 = fmaf(R.WC[m + 3], rhgs[m + 3], a3);
    }
    float hc = ftanh((a0 + a1) + (a2 + a3) + R.u4);
    float h = fmaf(zsw, hg - hc, hc);
    if (t >= t0 && lane < 16) out[(size_t)t * 16 + n] = h;
#pragma unroll
    for (int m = 0; m < 16; m++) hs[m] = RL(h, m);
}

__global__ __launch_bounds__(64) void k_walk_c(const float* __restrict__ ws,
                                               const float* __restrict__ gk,
                                               float* __restrict__ out) {
    const float* recb = ws + 1024;
    int lane = threadIdx.x;
    int n = lane & 15;
    int q = lane >> 4;
    int t0 = blockIdx.x * CHUNK;
    int te = t0 + CHUNK;
    int ts = t0 - W_WARM;
    if (ts < 0) ts = 0;
    RegsC Ra, Rb;
    load_step_c(recb, gk, ts, n, q, Ra);
    load_step_c(recb, gk, ts + 1, n, q, Rb);
    float hs[16];
#pragma unroll
    for (int m = 0; m < 16; m++) hs[m] = 0.f;
    for (int t = ts; t < te; t += 2) {
        wstep_c(Ra, hs, t, t0, lane, n, out);
        int tn = t + 2;
        load_step_c(recb, gk, tn < TT ? tn : TT - 1, n, q, Ra);
        wstep_c(Rb, hs, t + 1, t0, lane, n, out);
        int tm = t + 3;
        load_step_c(recb, gk, tm < TT ? tm : TT - 1, n, q, Rb);
    }
}

// ---------------------------------------------------------------------------
extern "C" void kernel_launch(void* const* d_in, const int* in_sizes, int n_in, void* d_out,
                              int out_size, void* d_ws, size_t ws_size, hipStream_t stream) {
    const float* inp = (const float*)d_in[0];
    const float* a = (const float*)d_in[1];
    const float* wx = (const float*)d_in[2];
    const float* bx = (const float*)d_in[3];
    const float* wh = (const float*)d_in[4];
    const float* bh = (const float*)d_in[5];
    const float* gk = (const float*)d_in[6];
    const float* gb = (const float*)d_in[7];
    float* out = (float*)d_out;
    float* ws = (float*)d_ws;

    size_t need = 4ull * (1024ull + (size_t)TT * RECF);  // ~71.3 MB
    k_fixed<<<dim3(1), dim3(256), 0, stream>>>(a, ws);
    if (ws_size >= need) {
        k_prep3<<<dim3(TT / 8), dim3(128), 0, stream>>>(inp, wx, bx, wh, bh, gk, gb, ws);
        k_walk3<<<dim3(TT / CHUNK), dim3(64), 0, stream>>>(ws, out);
    } else {
        k_prep_c<<<dim3(TT / 16), dim3(256), 0, stream>>>(inp, wx, bx, wh, bh, gk, gb, ws);
        k_walk_c<<<dim3(TT / CHUNK), dim3(64), 0, stream>>>(ws, gk, out);
    }
}